// Round 3
// baseline (146.247 us; speedup 1.0000x reference)
//
#include <hip/hip_runtime.h>

#define DIM 256
#define NHEADS 8
#define HDIM 32

typedef _Float16 half8_t __attribute__((ext_vector_type(8)));
typedef _Float16 half4_t __attribute__((ext_vector_type(4)));
typedef float float4_t __attribute__((ext_vector_type(4)));

__device__ __forceinline__ float fast_exp2(float x) {
#if __has_builtin(__builtin_amdgcn_exp2f)
    return __builtin_amdgcn_exp2f(x);
#else
    return __expf(x * 0.6931471805599453f);
#endif
}

__device__ __forceinline__ void gload_lds16(const void* g, void* l) {
    __builtin_amdgcn_global_load_lds((const __attribute__((address_space(1))) void*)g,
                                     (__attribute__((address_space(3))) void*)l,
                                     16, 0, 0);
}

// ---------------------------------------------------------------------------
// prep: (a) x fp32 -> fp16 flat; (b) Wqkv [256,768] -> WqT [768,256] fp16;
//       (c) Wout [256,256] -> WoT [256,256] fp16 (transposed for B-frags).
// ---------------------------------------------------------------------------
__global__ __launch_bounds__(256) void prep(const float* __restrict__ x,
                                            const float* __restrict__ Wqkv,
                                            const float* __restrict__ Wout,
                                            _Float16* __restrict__ xh,
                                            _Float16* __restrict__ WqT,
                                            _Float16* __restrict__ WoT) {
    __shared__ float ts[32][33];
    const int bid = blockIdx.x, t = threadIdx.x;
    if (bid < 1024) {
        size_t idx = (size_t)bid * 2048 + (size_t)t * 8;
        float tmp[8];
        *reinterpret_cast<float4*>(tmp)     = *reinterpret_cast<const float4*>(x + idx);
        *reinterpret_cast<float4*>(tmp + 4) = *reinterpret_cast<const float4*>(x + idx + 4);
        half8_t h;
        #pragma unroll
        for (int j = 0; j < 8; ++j) h[j] = (_Float16)tmp[j];
        *reinterpret_cast<half8_t*>(xh + idx) = h;
    } else {
        const float* src; _Float16* dst; int K, N, kb, nb;
        if (bid < 1024 + 192) { int b2 = bid - 1024; src = Wqkv; dst = WqT; K = 256; N = 768; nb = b2 % 24; kb = b2 / 24; }
        else                  { int b3 = bid - 1216; src = Wout; dst = WoT; K = 256; N = 256; nb = b3 % 8;  kb = b3 / 8; }
        const int tx = t & 31, ty = t >> 5;
        #pragma unroll
        for (int i = 0; i < 4; ++i) {
            int k = kb * 32 + ty + i * 8;
            ts[ty + i * 8][tx] = src[(size_t)k * N + nb * 32 + tx];
        }
        __syncthreads();
        #pragma unroll
        for (int i = 0; i < 4; ++i) {
            int nl = ty + i * 8;
            dst[(size_t)(nb * 32 + nl) * K + kb * 32 + tx] = (_Float16)ts[tx][nl];
        }
    }
}

// ---------------------------------------------------------------------------
// fp16 MFMA GEMM, LDS-staged: C[M,N] = A[M,K] @ BT[N,K]^T.
// MROWS*32 x 128 tile, BK=32, 4 waves, global_load_lds 16B staging.
// VSPLIT (qkv gemm): tiles with n0>=512 are V -> written TRANSPOSED to
// VT[b][h][hd][token]; Q columns (n0<256) are pre-scaled by scale*log2(e)
// so attention can use exp2 directly.
// ---------------------------------------------------------------------------
template <bool OUT_HALF, bool VSPLIT, int MROWS>
__global__ __launch_bounds__(256) void gemm_h(const _Float16* __restrict__ A,
                                              const _Float16* __restrict__ BT,
                                              const float* __restrict__ bias,
                                              void* __restrict__ Cv,
                                              _Float16* __restrict__ VTo,
                                              int M, int N, int K, int ldc) {
    constexpr int BM = MROWS * 32;
    __shared__ alignas(16) _Float16 As[BM * 32];
    __shared__ alignas(16) _Float16 Bs[128 * 32];
    const int t = threadIdx.x, lane = t & 63, wave = t >> 6;
    const int l16 = lane & 15, quad = lane >> 4;
    const int m0 = blockIdx.y * BM, n0 = blockIdx.x * 128;
    const int wr = (wave >> 1) * (MROWS * 16), wc = (wave & 1) * 64;
    constexpr float QS = 0.17677669529663687f * 1.4426950408889634f;  // scale*log2e
    float4_t acc[MROWS][4];
    #pragma unroll
    for (int i = 0; i < MROWS; ++i)
        #pragma unroll
        for (int j = 0; j < 4; ++j) acc[i][j] = (float4_t){0.f, 0.f, 0.f, 0.f};

    const int srow = lane >> 2;        // 0..15 within 16-row chunk
    const int scol = (lane & 3) * 8;   // halves

    for (int k0 = 0; k0 < K; k0 += 32) {
        #pragma unroll
        for (int i = 0; i < MROWS / 2; ++i) {
            int chunk = i * 4 + wave;
            int r = chunk * 16 + srow;
            gload_lds16(A + (size_t)(m0 + r) * K + k0 + scol, As + chunk * 512);
        }
        #pragma unroll
        for (int i = 0; i < 2; ++i) {
            int chunk = i * 4 + wave;
            int r = chunk * 16 + srow;
            gload_lds16(BT + (size_t)(n0 + r) * K + k0 + scol, Bs + chunk * 512);
        }
        __syncthreads();
        half8_t af[MROWS], bf[4];
        #pragma unroll
        for (int i = 0; i < MROWS; ++i)
            af[i] = *reinterpret_cast<const half8_t*>(As + (wr + i * 16 + l16) * 32 + quad * 8);
        #pragma unroll
        for (int j = 0; j < 4; ++j)
            bf[j] = *reinterpret_cast<const half8_t*>(Bs + (wc + j * 16 + l16) * 32 + quad * 8);
        #pragma unroll
        for (int i = 0; i < MROWS; ++i)
            #pragma unroll
            for (int j = 0; j < 4; ++j)
                acc[i][j] = __builtin_amdgcn_mfma_f32_16x16x32_f16(af[i], bf[j], acc[i][j], 0, 0, 0);
        __syncthreads();
    }

    if (VSPLIT && n0 >= 512) {
        // V tile: write transposed VT[b][h][hd][token], 4 tokens per b64 store.
        const int bb = m0 >> 11;
        const int tok0 = (m0 & 2047) + wr;
        #pragma unroll
        for (int i = 0; i < MROWS; ++i)
            #pragma unroll
            for (int j = 0; j < 4; ++j) {
                int vcol = n0 + wc + j * 16 + l16 - 512;
                int hh = vcol >> 5, d = vcol & 31;
                half4_t p;
                #pragma unroll
                for (int r = 0; r < 4; ++r) p[r] = (_Float16)acc[i][j][r];
                *reinterpret_cast<half4_t*>(
                    VTo + ((size_t)(bb * NHEADS + hh) * HDIM + d) * 2048
                        + tok0 + i * 16 + quad * 4) = p;
            }
    } else {
        float bv[4] = {0.f, 0.f, 0.f, 0.f};
        if (bias != nullptr) {
            #pragma unroll
            for (int j = 0; j < 4; ++j) bv[j] = bias[n0 + wc + j * 16 + l16];
        }
        #pragma unroll
        for (int i = 0; i < MROWS; ++i)
            #pragma unroll
            for (int r = 0; r < 4; ++r) {
                int row = m0 + wr + i * 16 + quad * 4 + r;
                #pragma unroll
                for (int j = 0; j < 4; ++j) {
                    int col = n0 + wc + j * 16 + l16;
                    float v = acc[i][j][r] + bv[j];
                    if (VSPLIT && n0 < 256) v *= QS;  // pre-scale Q for exp2
                    if (OUT_HALF) ((_Float16*)Cv)[(size_t)row * ldc + col] = (_Float16)v;
                    else          ((float*)Cv)[(size_t)row * ldc + col] = v;
                }
            }
    }
}

// ---------------------------------------------------------------------------
// MFMA flash attention v8b: no key-split (q-split x16 instead).
//  - each block: 128 q (4 waves x 32 q), ALL 2048 keys -> full denominator
//    in-register (ones-MFMA), normalize + write attnh fp16 directly.
//    Deletes NUM/DEN partial traffic (32MB) and the combine kernel.
//  - named-variable ping-pong prefetch (no arrays, no address-taken ->
//    guaranteed VGPR residency) hides L2 latency under exp/LDS/PV.
// Grid: 512 blocks = (b,h)[32] x 16 q-blocks(128).
// ---------------------------------------------------------------------------

// Load 64-key K/V fragments into 8 named half8 variables.
#define LOADKV(P, k0)                                                              \
    do {                                                                           \
        const _Float16* kp_ = kbase + (size_t)(k0) * 512;                          \
        k##P##0 = *reinterpret_cast<const half8_t*>(kp_);                          \
        k##P##1 = *reinterpret_cast<const half8_t*>(kp_ + (size_t)16 * 512);       \
        k##P##2 = *reinterpret_cast<const half8_t*>(kp_ + (size_t)32 * 512);       \
        k##P##3 = *reinterpret_cast<const half8_t*>(kp_ + (size_t)48 * 512);       \
        const _Float16* vp_ = vbase + (k0);                                        \
        v##P##0 = *reinterpret_cast<const half8_t*>(vp_);                          \
        v##P##1 = *reinterpret_cast<const half8_t*>(vp_ + (size_t)16 * 2048);      \
        v##P##2 = *reinterpret_cast<const half8_t*>(vp_ + 32);                     \
        v##P##3 = *reinterpret_cast<const half8_t*>(vp_ + 32 + (size_t)16 * 2048); \
    } while (0)

// One 16-key sub-block: S^T via MFMA, exp2, pack to half4 pair.
#define EXPKB(KF, e0, e1)                                                          \
    do {                                                                           \
        float4_t st0 = __builtin_amdgcn_mfma_f32_16x16x32_f16(KF, qf0, z, 0, 0, 0);\
        float4_t st1 = __builtin_amdgcn_mfma_f32_16x16x32_f16(KF, qf1, z, 0, 0, 0);\
        auto lo0 = __builtin_amdgcn_cvt_pkrtz(fast_exp2(st0[0]), fast_exp2(st0[1]));\
        auto hi0 = __builtin_amdgcn_cvt_pkrtz(fast_exp2(st0[2]), fast_exp2(st0[3]));\
        e0 = (half4_t){(_Float16)lo0[0], (_Float16)lo0[1],                         \
                       (_Float16)hi0[0], (_Float16)hi0[1]};                        \
        auto lo1 = __builtin_amdgcn_cvt_pkrtz(fast_exp2(st1[0]), fast_exp2(st1[1]));\
        auto hi1 = __builtin_amdgcn_cvt_pkrtz(fast_exp2(st1[2]), fast_exp2(st1[3]));\
        e1 = (half4_t){(_Float16)lo1[0], (_Float16)lo1[1],                         \
                       (_Float16)hi1[0], (_Float16)hi1[1]};                        \
    } while (0)

// 32-key chunk: E->LDS (b64), A-frags back (b128), PV + ones-MFMA denom.
#define PVCHUNK(ea0, ea1, eb0, eb1, VF0, VF1)                                      \
    do {                                                                           \
        *reinterpret_cast<half4_t*>(esw + l16 * 40 + quad * 4) = ea0;              \
        *reinterpret_cast<half4_t*>(esw + (16 + l16) * 40 + quad * 4) = ea1;       \
        *reinterpret_cast<half4_t*>(esw + l16 * 40 + 16 + quad * 4) = eb0;         \
        *reinterpret_cast<half4_t*>(esw + (16 + l16) * 40 + 16 + quad * 4) = eb1;  \
        half8_t ef0 = *reinterpret_cast<const half8_t*>(esw + l16 * 40 + quad * 8);\
        half8_t ef1 = *reinterpret_cast<const half8_t*>(esw + (16 + l16) * 40 + quad * 8);\
        num00 = __builtin_amdgcn_mfma_f32_16x16x32_f16(ef0, VF0, num00, 0, 0, 0);  \
        num01 = __builtin_amdgcn_mfma_f32_16x16x32_f16(ef0, VF1, num01, 0, 0, 0);  \
        dacc0 = __builtin_amdgcn_mfma_f32_16x16x32_f16(ef0, onef, dacc0, 0, 0, 0); \
        num10 = __builtin_amdgcn_mfma_f32_16x16x32_f16(ef1, VF0, num10, 0, 0, 0);  \
        num11 = __builtin_amdgcn_mfma_f32_16x16x32_f16(ef1, VF1, num11, 0, 0, 0);  \
        dacc1 = __builtin_amdgcn_mfma_f32_16x16x32_f16(ef1, onef, dacc1, 0, 0, 0); \
    } while (0)

// Full 64-key step from ping-pong bank P.
#define STEP(P)                                                                    \
    do {                                                                           \
        half4_t e00, e01, e10, e11, e20, e21, e30, e31;                            \
        EXPKB(k##P##0, e00, e01);                                                  \
        EXPKB(k##P##1, e10, e11);                                                  \
        EXPKB(k##P##2, e20, e21);                                                  \
        EXPKB(k##P##3, e30, e31);                                                  \
        PVCHUNK(e00, e01, e10, e11, v##P##0, v##P##1);                             \
        PVCHUNK(e20, e21, e30, e31, v##P##2, v##P##3);                             \
    } while (0)

__global__ __launch_bounds__(256, 2) void attn_v8(const _Float16* __restrict__ qkh,
                                                  const _Float16* __restrict__ VT,
                                                  _Float16* __restrict__ attnh) {
    __shared__ alignas(16) _Float16 es[4][32][40];
    const int bid = blockIdx.x;
    const int qb = bid & 15;
    const int bh = bid >> 4;
    const int b = bh >> 3, h = bh & 7;
    const int t = threadIdx.x, lane = t & 63, wave = t >> 6;
    const int l16 = lane & 15, quad = lane >> 4;
    const int bN = b * 2048;
    const int q0w = qb * 128 + wave * 32;

    // Q fragments (B-operand of S^T): pre-scaled by scale*log2e, in regs.
    half8_t qf0, qf1;
    {
        const _Float16* qrow = qkh + (size_t)(bN + q0w + l16) * 512 + h * HDIM + quad * 8;
        qf0 = *reinterpret_cast<const half8_t*>(qrow);
        qf1 = *reinterpret_cast<const half8_t*>(qrow + (size_t)16 * 512);
    }

    const _Float16* kbase = qkh + (size_t)(bN + l16) * 512 + 256 + h * HDIM + quad * 8;
    const _Float16* vbase = VT + (size_t)bh * HDIM * 2048 + (size_t)l16 * 2048 + quad * 8;

    float4_t num00 = {0.f, 0.f, 0.f, 0.f}, num01 = {0.f, 0.f, 0.f, 0.f};
    float4_t num10 = {0.f, 0.f, 0.f, 0.f}, num11 = {0.f, 0.f, 0.f, 0.f};
    float4_t dacc0 = {0.f, 0.f, 0.f, 0.f}, dacc1 = {0.f, 0.f, 0.f, 0.f};

    half8_t onef;
    #pragma unroll
    for (int j = 0; j < 8; ++j) onef[j] = (_Float16)1.0f;

    _Float16* esw = &es[wave][0][0];
    const float4_t z = {0.f, 0.f, 0.f, 0.f};

    // Named ping-pong: 32 chunks of 64 keys, prefetch next while computing.
    half8_t kA0, kA1, kA2, kA3, vA0, vA1, vA2, vA3;
    half8_t kB0, kB1, kB2, kB3, vB0, vB1, vB2, vB3;
    LOADKV(A, 0);
    #pragma unroll 2
    for (int k0 = 0; k0 < 2048; k0 += 128) {
        LOADKV(B, k0 + 64);
        STEP(A);
        if (k0 + 128 < 2048) LOADKV(A, k0 + 128);
        STEP(B);
    }

    // Normalize in-register and store attnh fp16 (no partials, no combine).
    _Float16* ob = attnh + (size_t)(bN + q0w) * DIM + h * HDIM;
    #pragma unroll
    for (int r = 0; r < 4; ++r) {
        float rcp0 = 1.0f / (dacc0[r] + 1e-6f);
        float rcp1 = 1.0f / (dacc1[r] + 1e-6f);
        size_t ro0 = (size_t)(quad * 4 + r) * DIM;
        size_t ro1 = (size_t)(16 + quad * 4 + r) * DIM;
        ob[ro0 + l16]      = (_Float16)(num00[r] * rcp0);
        ob[ro0 + 16 + l16] = (_Float16)(num01[r] * rcp0);
        ob[ro1 + l16]      = (_Float16)(num10[r] * rcp1);
        ob[ro1 + 16 + l16] = (_Float16)(num11[r] * rcp1);
    }
}

extern "C" void kernel_launch(void* const* d_in, const int* in_sizes, int n_in,
                              void* d_out, int out_size, void* d_ws, size_t ws_size,
                              hipStream_t stream) {
    const float* x    = (const float*)d_in[0];
    const float* Wqkv = (const float*)d_in[1];
    const float* Wout = (const float*)d_in[2];
    const float* bout = (const float*)d_in[3];
    float* out = (float*)d_out;
    const int M = 8192;

    _Float16* xh    = (_Float16*)d_ws;                 // [8192,256]
    _Float16* WqT   = xh + (size_t)M * DIM;            // [768,256]
    _Float16* WoT   = WqT + 768 * 256;                 // [256,256]
    _Float16* qkh   = WoT + 256 * 256;                 // [8192,512]  (Q|K)
    _Float16* vt    = qkh + (size_t)M * 512;           // [4][8][32][2048] V^T
    _Float16* attnh = vt + (size_t)32 * HDIM * 2048;   // [8192,256]

    hipLaunchKernelGGL(prep, dim3(1280), dim3(256), 0, stream, x, Wqkv, Wout, xh, WqT, WoT);
    // qkv GEMM: Q (scaled by scale*log2e), K -> qkh (ldc 512); V -> vt transposed.
    hipLaunchKernelGGL((gemm_h<true, true, 4>), dim3(6, 64), dim3(256), 0, stream,
                       xh, WqT, (const float*)nullptr, (void*)qkh, vt, M, 768, DIM, 512);
    // attention: full keys per block, normalized fp16 output (no combine).
    hipLaunchKernelGGL(attn_v8, dim3(512), dim3(256), 0, stream, qkh, vt, attnh);
    // out = attnh @ Wout + bout (fp32 out): 64-row M-tiles -> 256 balanced blocks.
    hipLaunchKernelGGL((gemm_h<false, false, 2>), dim3(2, 128), dim3(256), 0, stream,
                       attnh, WoT, bout, (void*)out, (_Float16*)nullptr, M, DIM, DIM, DIM);
}